// Round 2
// baseline (173.897 us; speedup 1.0000x reference)
//
#include <hip/hip_runtime.h>

// vol [B=2, 192,192,192, C=1] fp32, affine [B,3,4] fp32,
// out [B,192,192,192,1] fp32.
#define DIM   192
#define PLANE (DIM * DIM)
#define NB    2
#define DPT   4    // d-voxels per thread
#define BH    8    // h rows per block
#define BW    64   // w cols per block (one wave wide)
#define NTHREADS (BW * BH)   // 512

// Staged input slab (dynamically positioned per block from the affine).
// 80*16*12 floats = 61440 B static LDS -> 2 blocks/CU (122.9 KB of 160 KB).
#define SW 80
#define SH 16
#define SD 12
#define SPLANE (SH * SW)       // 1280
#define NELEM  (SD * SH * SW)  // 15360
#define NGROUP (NELEM / 4)     // 3840 float4 groups

typedef float f2 __attribute__((ext_vector_type(2), aligned(4)));
typedef float f4 __attribute__((ext_vector_type(4), aligned(16)));

// R1 post-mortem: runtime invariant under occupancy 72%<->37% and per-wave
// batching changes => the wall is per-CU vector-memory (TA) instruction
// throughput: 20 per-lane gather/store VMEM per thread. This version stages
// the block's input slab through LDS with ~8 wide dwordx4 loads/thread and
// serves the 16 corner reads from the DS pipe (separate from TA).
__global__ __launch_bounds__(NTHREADS) __attribute__((amdgpu_waves_per_eu(4, 4))) void
SpatialTransformer_warp_kernel(const float* __restrict__ vol,
                               const float* __restrict__ affine,
                               float* __restrict__ out) {
    __shared__ float lds[NELEM];

    const int tid = threadIdx.x;
    const int w   = blockIdx.x * BW + (tid & 63);
    const int h   = blockIdx.y * BH + (tid >> 6);
    const int z   = blockIdx.z;                       // (d-quad | b)
    const int b   = (z >= DIM / DPT) ? 1 : 0;
    const int d0  = (z - b * (DIM / DPT)) * DPT;

    const float* __restrict__ A = affine + b * 12;
    const float a00 = A[0], a01 = A[1], a02 = A[2],  a03 = A[3];
    const float a10 = A[4], a11 = A[5], a12 = A[6],  a13 = A[7];
    const float a20 = A[8], a21 = A[9], a22 = A[10], a23 = A[11];

    const float center = (DIM - 1) * 0.5f;   // 95.5
    const float maxl   = (float)(DIM - 1);   // 191.0
    const float maxi0  = (float)(DIM - 2);   // 190.0

    // ---- slab origin: transform the block's center, back off half a window.
    const float ccd = (float)d0 + (DPT - 1) * 0.5f - center;
    const float cch = (float)(blockIdx.y * BH) + (BH - 1) * 0.5f - center;
    const float ccw = (float)(blockIdx.x * BW) + (BW - 1) * 0.5f - center;

    const float lcd = a00 * ccd + a01 * cch + a02 * ccw + a03 + center;
    const float lch = a10 * ccd + a11 * cch + a12 * ccw + a13 + center;
    const float lcw = a20 * ccd + a21 * cch + a22 * ccw + a23 + center;

    const int od = (int)floorf(lcd) - (SD / 2 - 1);        // window [f-5, f+6]
    const int oh = (int)floorf(lch) - (SH / 2 - 1);        // window [f-7, f+8]
    const int ow = ((int)floorf(lcw) - 38) & ~3;           // 16B-aligned, [~f-38, ~f+41]

    const float* __restrict__ vb = vol + (size_t)b * DIM * PLANE;

    // ---- stage: 8 x dwordx4 per thread, clamped rows, splat at w-edges.
    // 192 % 4 == 0 and ow % 4 == 0 => every group is fully in-row, fully
    // below 0, or fully above 191 (no mixed groups).
#pragma unroll
    for (int i = 0; i < 8; ++i) {
        const int g = i * NTHREADS + tid;
        if (g < NGROUP) {
            const int rw4 = (g % (SW / 4)) << 2;
            const int t   = g / (SW / 4);
            const int rh  = t % SH;
            const int rd  = t / SH;
            int cd = od + rd; cd = cd < 0 ? 0 : (cd > DIM - 1 ? DIM - 1 : cd);
            int ch = oh + rh; ch = ch < 0 ? 0 : (ch > DIM - 1 ? DIM - 1 : ch);
            const int gw = ow + rw4;
            const float* rowp = vb + cd * PLANE + ch * DIM;
            f4 v;
            if ((unsigned)gw <= (unsigned)(DIM - 4)) {
                v = *(const f4*)(rowp + gw);
            } else {
                const float s = rowp[gw < 0 ? 0 : DIM - 1];
                v = (f4){s, s, s, s};
            }
            *(f4*)(&lds[g << 2]) = v;
        }
    }
    __syncthreads();

    // ---- consume ----
    const float chh = (float)h - center;
    const float cww = (float)w - center;
    const float pd = a01 * chh + a02 * cww + a03 + center;
    const float ph = a11 * chh + a12 * cww + a13 + center;
    const float pw = a21 * chh + a22 * cww + a23 + center;

    float* __restrict__ ob = out + ((size_t)b * DIM + d0) * PLANE
                                 + (size_t)h * DIM + w;

#pragma unroll
    for (int k = 0; k < DPT; ++k) {
        const float cd = (float)(d0 + k) - center;
        const float ld = a00 * cd + pd;
        const float lh = a10 * cd + ph;
        const float lw = a20 * cd + pw;

        // i0 = min(floor(clamp(l,0,191)),190); i1 = i0+1; w0 = i0+1 - clamp(l).
        const float td = __builtin_amdgcn_fmed3f(ld, 0.0f, maxl);
        const float th = __builtin_amdgcn_fmed3f(lh, 0.0f, maxl);
        const float tw = __builtin_amdgcn_fmed3f(lw, 0.0f, maxl);

        const float fd = fminf(floorf(td), maxi0);
        const float fh = fminf(floorf(th), maxi0);
        const float fw = fminf(floorf(tw), maxi0);

        const float w0d = fd + 1.0f - td;
        const float w0h = fh + 1.0f - th;
        const float w0w = fw + 1.0f - tw;

        const int ifd = (int)fd, ifh = (int)fh, ifw = (int)fw;
        const int rd = ifd - od, rh = ifh - oh, rw = ifw - ow;

        float v00x, v00y, v01x, v01y, v10x, v10y, v11x, v11y;
        if ((unsigned)rd <= (unsigned)(SD - 2) &&
            (unsigned)rh <= (unsigned)(SH - 2) &&
            (unsigned)rw <= (unsigned)(SW - 2)) {
            const float* p = &lds[rd * SPLANE + rh * SW + rw];
            v00x = p[0];           v00y = p[1];
            v01x = p[SW];          v01y = p[SW + 1];
            v10x = p[SPLANE];      v10y = p[SPLANE + 1];
            v11x = p[SPLANE + SW]; v11y = p[SPLANE + SW + 1];
        } else {
            // exact fallback: rare lanes whose displaced cube misses the slab
            const float* p = vb + (ifd * PLANE + ifh * DIM + ifw);
            const f2 r00 = *(const f2*)(p);
            const f2 r01 = *(const f2*)(p + DIM);
            const f2 r10 = *(const f2*)(p + PLANE);
            const f2 r11 = *(const f2*)(p + PLANE + DIM);
            v00x = r00.x; v00y = r00.y;
            v01x = r01.x; v01y = r01.y;
            v10x = r10.x; v10y = r10.y;
            v11x = r11.x; v11y = r11.y;
        }

        const float w1w = 1.0f - w0w;
        const float w1h = 1.0f - w0h;
        const float w1d = 1.0f - w0d;

        const float x00 = v00x * w0w + v00y * w1w;
        const float x01 = v01x * w0w + v01y * w1w;
        const float x10 = v10x * w0w + v10y * w1w;
        const float x11 = v11x * w0w + v11y * w1w;

        const float y0 = x00 * w0h + x01 * w1h;
        const float y1 = x10 * w0h + x11 * w1h;

        __builtin_nontemporal_store(y0 * w0d + y1 * w1d, ob + k * PLANE);
    }
}

extern "C" void kernel_launch(void* const* d_in, const int* in_sizes, int n_in,
                              void* d_out, int out_size, void* d_ws, size_t ws_size,
                              hipStream_t stream) {
    const float* vol    = (const float*)d_in[0];
    const float* affine = (const float*)d_in[1];
    float* out = (float*)d_out;

    dim3 grid(DIM / BW, DIM / BH, NB * (DIM / DPT));  // (3, 24, 96)
    dim3 block(NTHREADS);
    SpatialTransformer_warp_kernel<<<grid, block, 0, stream>>>(vol, affine, out);
}

// Round 3
// 127.785 us; speedup vs baseline: 1.3609x; 1.3609x over previous
//
#include <hip/hip_runtime.h>

// vol [B=2, 192,192,192, C=1] fp32, affine [B,3,4] fp32,
// out [B,192,192,192,1] fp32.
#define DIM   192
#define PLANE (DIM * DIM)
#define NB    2
#define DPT   4   // d-voxels per thread
#define BH    4   // h rows per block

typedef float f2 __attribute__((ext_vector_type(2), aligned(4)));
typedef float f4 __attribute__((ext_vector_type(4), aligned(4)));  // 4B-aligned: HW unaligned vector load

// R2 post-mortem: LDS staging doubled HBM fetch (halo) + tripled VALU + bank
// conflicts -> reverted. R0/R1 invariance (occupancy 72<->37%, batching) says
// the wall is TA address throughput (~16 cy per wave64 VMEM instr):
// 20 VMEM/thread * 16 cy * 216 waves/CU ~= 69K of the 113K cycles.
// This version: 2 w-outputs per thread, corner loads shared as one dwordx4
// per (plane,row) covering both outputs' 2-float windows (share rate ~96%;
// per-lane dwordx2 fallback otherwise). VMEM addr-cycles/output: 5.0 -> ~2.6.
__global__ __launch_bounds__(96 * BH) __attribute__((amdgpu_waves_per_eu(3, 8))) void
SpatialTransformer_warp_kernel(const float* __restrict__ vol,
                               const float* __restrict__ affine,
                               float* __restrict__ out) {
    const int q  = threadIdx.x;                    // w-pair index 0..95
    const int h  = blockIdx.x * BH + threadIdx.y;  // h row
    const int z  = blockIdx.y;                     // (d-quad | b)
    const int b  = (z >= DIM / DPT) ? 1 : 0;
    const int d0 = (z - b * (DIM / DPT)) * DPT;
    const int w0 = q << 1;

    const float* __restrict__ A = affine + b * 12;
    const float a00 = A[0], a01 = A[1], a02 = A[2],  a03 = A[3];
    const float a10 = A[4], a11 = A[5], a12 = A[6],  a13 = A[7];
    const float a20 = A[8], a21 = A[9], a22 = A[10], a23 = A[11];

    const float center = (DIM - 1) * 0.5f;   // 95.5
    const float maxl   = (float)(DIM - 1);   // 191.0
    const float maxi0  = (float)(DIM - 2);   // 190.0
    const float fplane = (float)PLANE;       // 36864.0
    const float fdim   = (float)DIM;         // 192.0

    const float ch  = (float)h  - center;
    const float cw0 = (float)w0 - center;

    // Partial sums (d-independent); output1 = output0 + w-column of A
    const float pd0 = a01 * ch + a02 * cw0 + a03 + center;
    const float ph0 = a11 * ch + a12 * cw0 + a13 + center;
    const float pw0 = a21 * ch + a22 * cw0 + a23 + center;
    const float pd1 = pd0 + a02;
    const float ph1 = ph0 + a12;
    const float pw1 = pw0 + a22;

    const float* __restrict__ vb = vol + (size_t)b * DIM * PLANE;
    float* __restrict__ ob = out + ((size_t)b * DIM + d0) * PLANE
                                 + (size_t)h * DIM + w0;

#pragma unroll
    for (int k = 0; k < DPT; ++k) {
        const float cd = (float)(d0 + k) - center;

        // Reference semantics (proven in R0/R1): t = clamp(l,0,191);
        // f = min(floor(t),190); i1 = f+1; floor-corner weight = f+1-t.
        const float td0 = __builtin_amdgcn_fmed3f(__builtin_fmaf(a00, cd, pd0), 0.0f, maxl);
        const float th0 = __builtin_amdgcn_fmed3f(__builtin_fmaf(a10, cd, ph0), 0.0f, maxl);
        const float tw0 = __builtin_amdgcn_fmed3f(__builtin_fmaf(a20, cd, pw0), 0.0f, maxl);
        const float td1 = __builtin_amdgcn_fmed3f(__builtin_fmaf(a00, cd, pd1), 0.0f, maxl);
        const float th1 = __builtin_amdgcn_fmed3f(__builtin_fmaf(a10, cd, ph1), 0.0f, maxl);
        const float tw1 = __builtin_amdgcn_fmed3f(__builtin_fmaf(a20, cd, pw1), 0.0f, maxl);

        const float fd0  = fminf(floorf(td0), maxi0);
        const float fh0  = fminf(floorf(th0), maxi0);
        const float fw0c = fminf(floorf(tw0), maxi0);
        const float fd1  = fminf(floorf(td1), maxi0);
        const float fh1  = fminf(floorf(th1), maxi0);
        const float fw1c = fminf(floorf(tw1), maxi0);

        // Shared 4-float window base, clamped to 188 so base+3 stays inside
        // the row AND the final load (+PLANE+DIM+12B) stays inside the buffer.
        const float fbw = fminf(fw0c, (float)(DIM - 4));
        const int base = (int)__builtin_fmaf(fd0, fplane, __builtin_fmaf(fh0, fdim, fbw));
        const float* p = vb + base;

        const f4 vA = *(const f4*)(p);                 // (fd0,   fh0,   fbw..+3)
        const f4 vB = *(const f4*)(p + DIM);           // (fd0,   fh0+1)
        const f4 vC = *(const f4*)(p + PLANE);         // (fd0+1, fh0)
        const f4 vD = *(const f4*)(p + PLANE + DIM);   // (fd0+1, fh0+1)

        // ---- output 0: offset fo0 == 0 except right-edge lanes (fw0c>188);
        // wave-uniform skip of the cndmask extraction in the common case.
        const float fo0 = fw0c - fbw;
        float A0x = vA.x, A0y = vA.y, B0x = vB.x, B0y = vB.y;
        float C0x = vC.x, C0y = vC.y, D0x = vD.x, D0y = vD.y;
        if (__any(fo0 != 0.0f)) {
            const bool g1 = (fo0 == 1.0f), g2 = (fo0 == 2.0f);
            A0x = g2 ? vA.z : (g1 ? vA.y : vA.x);  A0y = g2 ? vA.w : (g1 ? vA.z : vA.y);
            B0x = g2 ? vB.z : (g1 ? vB.y : vB.x);  B0y = g2 ? vB.w : (g1 ? vB.z : vB.y);
            C0x = g2 ? vC.z : (g1 ? vC.y : vC.x);  C0y = g2 ? vC.w : (g1 ? vC.z : vC.y);
            D0x = g2 ? vD.z : (g1 ? vD.y : vD.x);  D0y = g2 ? vD.w : (g1 ? vD.z : vD.y);
        }

        // ---- output 1: shared-window extraction (~96% of lanes), else
        // exact per-lane dwordx2 fallback (exec-masked, R1's path).
        const float fo1 = fw1c - fbw;
        const bool share = (fd1 == fd0) & (fh1 == fh0) & (fo1 >= 0.0f) & (fo1 <= 2.0f);
        float A1x, A1y, B1x, B1y, C1x, C1y, D1x, D1y;
        if (share) {
            const bool e1 = (fo1 == 1.0f), e2 = (fo1 == 2.0f);
            A1x = e2 ? vA.z : (e1 ? vA.y : vA.x);  A1y = e2 ? vA.w : (e1 ? vA.z : vA.y);
            B1x = e2 ? vB.z : (e1 ? vB.y : vB.x);  B1y = e2 ? vB.w : (e1 ? vB.z : vB.y);
            C1x = e2 ? vC.z : (e1 ? vC.y : vC.x);  C1y = e2 ? vC.w : (e1 ? vC.z : vC.y);
            D1x = e2 ? vD.z : (e1 ? vD.y : vD.x);  D1y = e2 ? vD.w : (e1 ? vD.z : vD.y);
        } else {
            const int i1 = (int)__builtin_fmaf(fd1, fplane, __builtin_fmaf(fh1, fdim, fw1c));
            const float* p1 = vb + i1;
            const f2 tA = *(const f2*)(p1);
            const f2 tB = *(const f2*)(p1 + DIM);
            const f2 tC = *(const f2*)(p1 + PLANE);
            const f2 tD = *(const f2*)(p1 + PLANE + DIM);
            A1x = tA.x; A1y = tA.y;  B1x = tB.x; B1y = tB.y;
            C1x = tC.x; C1y = tC.y;  D1x = tD.x; D1y = tD.y;
        }

        // ---- weights + trilinear (same expression order as R1 -> same absmax)
        const float u0 = fw0c + 1.0f - tw0, u1 = 1.0f - u0;
        const float v0 = fh0  + 1.0f - th0, v1 = 1.0f - v0;
        const float s0 = fd0  + 1.0f - td0, s1 = 1.0f - s0;
        const float U0 = fw1c + 1.0f - tw1, U1 = 1.0f - U0;
        const float V0 = fh1  + 1.0f - th1, V1 = 1.0f - V0;
        const float S0 = fd1  + 1.0f - td1, S1 = 1.0f - S0;

        const float x00 = A0x * u0 + A0y * u1;
        const float x01 = B0x * u0 + B0y * u1;
        const float x10 = C0x * u0 + C0y * u1;
        const float x11 = D0x * u0 + D0y * u1;
        const float r0 = (x00 * v0 + x01 * v1) * s0 + (x10 * v0 + x11 * v1) * s1;

        const float X00 = A1x * U0 + A1y * U1;
        const float X01 = B1x * U0 + B1y * U1;
        const float X10 = C1x * U0 + C1y * U1;
        const float X11 = D1x * U0 + D1y * U1;
        const float r1 = (X00 * V0 + X01 * V1) * S0 + (X10 * V0 + X11 * V1) * S1;

        __builtin_nontemporal_store((f2){r0, r1}, (f2*)(ob + k * PLANE));
    }
}

extern "C" void kernel_launch(void* const* d_in, const int* in_sizes, int n_in,
                              void* d_out, int out_size, void* d_ws, size_t ws_size,
                              hipStream_t stream) {
    const float* vol    = (const float*)d_in[0];
    const float* affine = (const float*)d_in[1];
    float* out = (float*)d_out;

    dim3 grid(DIM / BH, NB * (DIM / DPT));   // (48, 96)
    dim3 block(96, BH);                      // 384 threads: 96 w-pairs x 4 h rows
    SpatialTransformer_warp_kernel<<<grid, block, 0, stream>>>(vol, affine, out);
}